// Round 5
// baseline (552.776 us; speedup 1.0000x reference)
//
#include <hip/hip_runtime.h>

#define N_NODES 100000
#define N_EDGES 800000
#define NEG 0.2f
#define BKT_SHIFT 7
#define BKT_NODES 128
#define N_BKT ((N_NODES + BKT_NODES - 1) / BKT_NODES)   // 782

typedef __attribute__((ext_vector_type(8))) short bf16x8;
typedef __attribute__((ext_vector_type(4))) float f32x4;

__device__ inline unsigned short f2bf(float f) {   // RNE f32 -> bf16
    unsigned u = __float_as_uint(f);
    u += 0x7fffu + ((u >> 16) & 1u);
    return (unsigned short)(u >> 16);
}
__device__ inline float bf2f_lo(unsigned u) { return __uint_as_float(u << 16); }
__device__ inline float bf2f_hi(unsigned u) { return __uint_as_float(u & 0xffff0000u); }

// ---------------------------------------------------------------------------
// prep_x: x f32 -> bf16 (shared by both GEMM directions)
// ---------------------------------------------------------------------------
__global__ __launch_bounds__(256) void prep_x_kernel(
    const float* __restrict__ x, unsigned short* __restrict__ x_bf)
{
    const int i = (blockIdx.x * 256 + threadIdx.x) * 4;
    if (i >= N_NODES * 128) return;
    const float4 v = *(const float4*)&x[i];
    ushort4 o;
    o.x = f2bf(v.x); o.y = f2bf(v.y); o.z = f2bf(v.z); o.w = f2bf(v.w);
    *(ushort4*)&x_bf[i] = o;
}

// ---------------------------------------------------------------------------
// prep_w: pack W (and Aalpha = W·a vectors, ct==8) into MFMA B-fragment order.
// ---------------------------------------------------------------------------
__global__ __launch_bounds__(256) void prep_w_kernel(
    const float* __restrict__ W_in, const float* __restrict__ W_out,
    const float* __restrict__ as_in, const float* __restrict__ ad_in,
    const float* __restrict__ as_out, const float* __restrict__ ad_out,
    unsigned short* __restrict__ Wf)
{
    const int t = blockIdx.x * 256 + threadIdx.x;
    if (t >= 2 * 4 * 9 * 64) return;
    const int lane = t & 63;
    const int rest = t >> 6;
    const int ct  = rest % 9;
    const int kb  = (rest / 9) & 3;
    const int dir = rest / 36;
    const float* W  = dir ? W_out  : W_in;
    const float* as = dir ? as_out : as_in;
    const float* ad = dir ? ad_out : ad_in;
    const int m16 = lane & 15, quad = lane >> 4;

    bf16x8 o;
#pragma unroll
    for (int j = 0; j < 8; ++j) {
        const int k = kb * 32 + quad * 8 + j;
        float v;
        if (ct < 8) {
            v = W[k * 128 + ct * 16 + m16];
        } else {
            const float* av = (m16 < 8) ? as : ad;
            const int hh = m16 & 7;
            v = 0.f;
            for (int c = 0; c < 16; ++c)
                v += W[k * 128 + hh * 16 + c] * av[hh * 16 + c];
        }
        o[j] = (short)f2bf(v);
    }
    *(bf16x8*)&Wf[(long long)t * 8] = o;
}

// ---------------------------------------------------------------------------
// gemm: h = bf16(x) @ bf16(W) via MFMA; alpha logits from the 9th column tile.
// ---------------------------------------------------------------------------
__global__ __launch_bounds__(256) void gemm_kernel(
    const unsigned short* __restrict__ x_bf,
    const unsigned short* __restrict__ Wf,
    unsigned short* __restrict__ h_in, unsigned short* __restrict__ h_out,
    float* __restrict__ asrc_in, float* __restrict__ adst_in,
    float* __restrict__ asrc_out, float* __restrict__ adst_out)
{
    const int dir = blockIdx.y;
    unsigned short* h = dir ? h_out : h_in;
    float* asrc = dir ? asrc_out : asrc_in;
    float* adst = dir ? adst_out : adst_in;

    const int tid  = threadIdx.x;
    const int lane = tid & 63;
    const int wave = tid >> 6;
    const int m16  = lane & 15;
    const int quad = lane >> 4;
    const int rbase = blockIdx.x * 128 + wave * 32;

    f32x4 acc[2][8];
    f32x4 acc_a[2];
#pragma unroll
    for (int rt = 0; rt < 2; ++rt) {
        acc_a[rt] = f32x4{0.f, 0.f, 0.f, 0.f};
#pragma unroll
        for (int ct = 0; ct < 8; ++ct)
            acc[rt][ct] = f32x4{0.f, 0.f, 0.f, 0.f};
    }

    const unsigned short* wf = Wf + (long long)dir * 4 * 9 * 64 * 8;

#pragma unroll
    for (int kb = 0; kb < 4; ++kb) {
        const int k0 = kb * 32 + quad * 8;
        bf16x8 a[2];
#pragma unroll
        for (int rt = 0; rt < 2; ++rt) {
            int r = rbase + rt * 16 + m16;
            r = r < N_NODES ? r : N_NODES - 1;   // clamp: stores are guarded
            a[rt] = *(const bf16x8*)&x_bf[(long long)r * 128 + k0];
        }
#pragma unroll
        for (int ct = 0; ct < 9; ++ct) {
            const bf16x8 b = *(const bf16x8*)&wf[(long long)((kb * 9 + ct) * 64 + lane) * 8];
            if (ct < 8) {
                acc[0][ct] = __builtin_amdgcn_mfma_f32_16x16x32_bf16(a[0], b, acc[0][ct], 0, 0, 0);
                acc[1][ct] = __builtin_amdgcn_mfma_f32_16x16x32_bf16(a[1], b, acc[1][ct], 0, 0, 0);
            } else {
                acc_a[0] = __builtin_amdgcn_mfma_f32_16x16x32_bf16(a[0], b, acc_a[0], 0, 0, 0);
                acc_a[1] = __builtin_amdgcn_mfma_f32_16x16x32_bf16(a[1], b, acc_a[1], 0, 0, 0);
            }
        }
    }

#pragma unroll
    for (int rt = 0; rt < 2; ++rt) {
#pragma unroll
        for (int r = 0; r < 4; ++r) {
            const int row = rbase + rt * 16 + quad * 4 + r;
            if (row < N_NODES) {
                unsigned short* hp = &h[(long long)row * 128 + m16];
#pragma unroll
                for (int ct = 0; ct < 8; ++ct)
                    hp[ct * 16] = f2bf(acc[rt][ct][r]);
                const float av = acc_a[rt][r];
                if (m16 < 8) asrc[row * 8 + m16] = av;
                else         adst[row * 8 + (m16 - 8)] = av;
            }
        }
    }
}

// ---------------------------------------------------------------------------
// CSR build v2: bucket binning (128-node buckets) to kill write amplification.
// ---------------------------------------------------------------------------
__global__ __launch_bounds__(256) void zero_bcnt_kernel(int* __restrict__ bcnt)
{
    const int i = blockIdx.x * 256 + threadIdx.x;
    if (i < 2 * N_BKT) bcnt[i] = 0;
}

// per-block LDS bucket histogram, flushed with low-contention global atomics
__global__ __launch_bounds__(256) void bucket_hist_kernel(
    const int* __restrict__ ei, int* __restrict__ bcnt)
{
    __shared__ int bh[2 * N_BKT];
    const int tid = threadIdx.x;
    for (int i = tid; i < 2 * N_BKT; i += 256) bh[i] = 0;
    __syncthreads();
    for (int e = blockIdx.x * 256 + tid; e < N_EDGES; e += gridDim.x * 256) {
        const int s = ei[e];
        const int t = ei[N_EDGES + e];
        atomicAdd(&bh[t >> BKT_SHIFT], 1);              // dir0: group by dst
        atomicAdd(&bh[N_BKT + (s >> BKT_SHIFT)], 1);    // dir1: group by src
    }
    __syncthreads();
    for (int i = tid; i < 2 * N_BKT; i += 256) {
        const int v = bh[i];
        if (v) atomicAdd(&bcnt[i], v);
    }
}

// scan bucket counts -> bucket offsets + cursors; also offs[N]=E
__global__ __launch_bounds__(1024) void bucket_scan_kernel(
    const int* __restrict__ bcnt,
    int* __restrict__ boffs0, int* __restrict__ boffs1,
    int* __restrict__ bcur0, int* __restrict__ bcur1,
    int* __restrict__ offs_in, int* __restrict__ offs_out)
{
    const int dir = blockIdx.x;
    const int* c = bcnt + dir * N_BKT;
    int* bo = dir ? boffs1 : boffs0;
    int* bc = dir ? bcur1  : bcur0;

    __shared__ int sm[1024];
    const int tid = threadIdx.x;
    const int v = (tid < N_BKT) ? c[tid] : 0;
    sm[tid] = v;
    __syncthreads();
#pragma unroll
    for (int off = 1; off < 1024; off <<= 1) {
        int t = (tid >= off) ? sm[tid - off] : 0;
        __syncthreads();
        sm[tid] += t;
        __syncthreads();
    }
    if (tid < N_BKT) {
        const int excl = sm[tid] - v;
        bo[tid] = excl;
        bc[tid] = excl;
    }
    if (tid == N_BKT - 1) bo[N_BKT] = sm[tid];   // == N_EDGES
    if (tid == 0) (dir ? offs_out : offs_in)[N_NODES] = N_EDGES;
}

// append (neighbor, key) pairs into per-bucket regions (dense appends)
__global__ __launch_bounds__(256) void bin_kernel(
    const int* __restrict__ ei,
    int* __restrict__ bcur0, int* __restrict__ bcur1,
    int2* __restrict__ binned0, int2* __restrict__ binned1)
{
    const int e = blockIdx.x * 256 + threadIdx.x;
    if (e >= N_EDGES) return;
    const int s = ei[e];
    const int t = ei[N_EDGES + e];
    const int p0 = atomicAdd(&bcur0[t >> BKT_SHIFT], 1);
    binned0[p0] = int2{s, t};
    const int p1 = atomicAdd(&bcur1[s >> BKT_SHIFT], 1);
    binned1[p1] = int2{t, s};
}

// one block per bucket: fine counts+scan+cursors in LDS; adj writes L2-local
__global__ __launch_bounds__(256) void place_kernel(
    const int2* __restrict__ binned0, const int2* __restrict__ binned1,
    const int* __restrict__ boffs0, const int* __restrict__ boffs1,
    int* __restrict__ adj_in, int* __restrict__ adj_out,
    int* __restrict__ offs_in, int* __restrict__ offs_out)
{
    const int b   = blockIdx.x;
    const int dir = blockIdx.y;
    const int2* bp = dir ? binned1 : binned0;
    const int* bo  = dir ? boffs1  : boffs0;
    int* adj  = dir ? adj_out  : adj_in;
    int* offs = dir ? offs_out : offs_in;

    const int base = b << BKT_SHIFT;
    const int beg = bo[b], end = bo[b + 1];
    const int tid = threadIdx.x;

    __shared__ int cnt[BKT_NODES];
    __shared__ int sc[BKT_NODES];
    __shared__ int cur[BKT_NODES];

    if (tid < BKT_NODES) cnt[tid] = 0;
    __syncthreads();
    for (int p = beg + tid; p < end; p += 256)
        atomicAdd(&cnt[bp[p].y - base], 1);
    __syncthreads();
    if (tid < BKT_NODES) sc[tid] = cnt[tid];
    __syncthreads();
#pragma unroll
    for (int off = 1; off < BKT_NODES; off <<= 1) {
        int t = 0;
        if (tid < BKT_NODES && tid >= off) t = sc[tid - off];
        __syncthreads();
        if (tid < BKT_NODES) sc[tid] += t;
        __syncthreads();
    }
    if (tid < BKT_NODES) {
        const int excl = beg + sc[tid] - cnt[tid];
        cur[tid] = excl;
        const int node = base + tid;
        if (node < N_NODES) offs[node] = excl;
    }
    __syncthreads();
    for (int p = beg + tid; p < end; p += 256) {
        const int2 pr = bp[p];
        const int pos = atomicAdd(&cur[pr.y - base], 1);
        adj[pos] = pr.x;
    }
}

// ---------------------------------------------------------------------------
// Gather: one wave per node, both directions + bias, unrolled x4 for MLP.
// ---------------------------------------------------------------------------
__global__ __launch_bounds__(256) void gather_kernel(
    const int* __restrict__ offs_in, const int* __restrict__ adj_in,
    const int* __restrict__ offs_out, const int* __restrict__ adj_out,
    const unsigned short* __restrict__ h_in, const unsigned short* __restrict__ h_out,
    const float* __restrict__ asrc_in, const float* __restrict__ adst_in,
    const float* __restrict__ asrc_out, const float* __restrict__ adst_out,
    const float* __restrict__ b_in, const float* __restrict__ b_out,
    float* __restrict__ out)
{
    const int n = (blockIdx.x * 256 + threadIdx.x) >> 6;
    if (n >= N_NODES) return;
    const int lane = threadIdx.x & 63;
    const int c0 = lane * 2;
    const int hh = lane >> 3;

    float acc0 = b_in[c0] + b_out[c0];
    float acc1 = b_in[c0 + 1] + b_out[c0 + 1];

#define DIR_BLOCK(OFFS, ADJ, HX, ASRC, ADST)                                   \
    {                                                                          \
        const int beg = OFFS[n], end = OFFS[n + 1];                            \
        if (end > beg) {                                                       \
            const float ad = ADST[n * 8 + hh];                                 \
            float num0 = 0.f, num1 = 0.f, den = 0.f;                           \
            int p = beg;                                                       \
            for (; p + 4 <= end; p += 4) {                                     \
                const int nb0 = ADJ[p], nb1 = ADJ[p + 1];                      \
                const int nb2 = ADJ[p + 2], nb3 = ADJ[p + 3];                  \
                const float s0 = ASRC[nb0 * 8 + hh], s1 = ASRC[nb1 * 8 + hh];  \
                const float s2 = ASRC[nb2 * 8 + hh], s3 = ASRC[nb3 * 8 + hh];  \
                const unsigned v0 = *(const unsigned*)&HX[(long long)nb0 * 128 + c0]; \
                const unsigned v1 = *(const unsigned*)&HX[(long long)nb1 * 128 + c0]; \
                const unsigned v2 = *(const unsigned*)&HX[(long long)nb2 * 128 + c0]; \
                const unsigned v3 = *(const unsigned*)&HX[(long long)nb3 * 128 + c0]; \
                float l0 = s0 + ad; l0 = l0 > 0.f ? l0 : NEG * l0;             \
                float l1 = s1 + ad; l1 = l1 > 0.f ? l1 : NEG * l1;             \
                float l2 = s2 + ad; l2 = l2 > 0.f ? l2 : NEG * l2;             \
                float l3 = s3 + ad; l3 = l3 > 0.f ? l3 : NEG * l3;             \
                const float w0 = __expf(l0), w1 = __expf(l1);                  \
                const float w2 = __expf(l2), w3 = __expf(l3);                  \
                den += (w0 + w1) + (w2 + w3);                                  \
                num0 += w0 * bf2f_lo(v0) + w1 * bf2f_lo(v1)                    \
                      + w2 * bf2f_lo(v2) + w3 * bf2f_lo(v3);                   \
                num1 += w0 * bf2f_hi(v0) + w1 * bf2f_hi(v1)                    \
                      + w2 * bf2f_hi(v2) + w3 * bf2f_hi(v3);                   \
            }                                                                  \
            for (; p < end; ++p) {                                             \
                const int nb = ADJ[p];                                         \
                float l = ASRC[nb * 8 + hh] + ad;                              \
                l = l > 0.f ? l : NEG * l;                                     \
                const float w = __expf(l);                                     \
                den += w;                                                      \
                const unsigned hv = *(const unsigned*)&HX[(long long)nb * 128 + c0]; \
                num0 += w * bf2f_lo(hv);                                       \
                num1 += w * bf2f_hi(hv);                                       \
            }                                                                  \
            acc0 += num0 / den;                                                \
            acc1 += num1 / den;                                                \
        }                                                                      \
    }

    DIR_BLOCK(offs_in, adj_in, h_in, asrc_in, adst_in)
    DIR_BLOCK(offs_out, adj_out, h_out, asrc_out, adst_out)
#undef DIR_BLOCK

    *(float2*)&out[(long long)n * 128 + c0] = float2{acc0, acc1};
}

extern "C" void kernel_launch(void* const* d_in, const int* in_sizes, int n_in,
                              void* d_out, int out_size, void* d_ws, size_t ws_size,
                              hipStream_t stream) {
    const float* x      = (const float*)d_in[0];
    const int*   ei     = (const int*)  d_in[1];
    const float* W_in   = (const float*)d_in[2];
    const float* as_in  = (const float*)d_in[3];
    const float* ad_in  = (const float*)d_in[4];
    const float* b_in   = (const float*)d_in[5];
    const float* W_out  = (const float*)d_in[6];
    const float* as_out = (const float*)d_in[7];
    const float* ad_out = (const float*)d_in[8];
    const float* b_out  = (const float*)d_in[9];
    float* out = (float*)d_out;

    // workspace layout (8B-aligned first, then 4B arrays)
    char* ws = (char*)d_ws;
    const long long NH = (long long)N_NODES * 128;
    unsigned short* x_bf  = (unsigned short*)ws;    ws += NH * 2;
    unsigned short* h_in  = (unsigned short*)ws;    ws += NH * 2;
    unsigned short* h_out = (unsigned short*)ws;    ws += NH * 2;
    unsigned short* Wf    = (unsigned short*)ws;    ws += 2LL * 4 * 9 * 64 * 8 * 2;
    int2* binned0    = (int2*)ws;                   ws += (long long)N_EDGES * 8;
    int2* binned1    = (int2*)ws;                   ws += (long long)N_EDGES * 8;
    float* asrc_in   = (float*)ws;                  ws += N_NODES * 8 * 4;
    float* adst_in   = (float*)ws;                  ws += N_NODES * 8 * 4;
    float* asrc_out  = (float*)ws;                  ws += N_NODES * 8 * 4;
    float* adst_out  = (float*)ws;                  ws += N_NODES * 8 * 4;
    int* adj_in      = (int*)ws;                    ws += N_EDGES * 4;
    int* adj_out     = (int*)ws;                    ws += N_EDGES * 4;
    int* offs_in     = (int*)ws;                    ws += (N_NODES + 1) * 4;
    int* offs_out    = (int*)ws;                    ws += (N_NODES + 1) * 4;
    int* bcnt        = (int*)ws;                    ws += 2 * N_BKT * 4;
    int* boffs0      = (int*)ws;                    ws += (N_BKT + 1) * 4;
    int* boffs1      = (int*)ws;                    ws += (N_BKT + 1) * 4;
    int* bcur0       = (int*)ws;                    ws += N_BKT * 4;
    int* bcur1       = (int*)ws;                    ws += N_BKT * 4;

    prep_x_kernel<<<(N_NODES * 128 / 4 + 255) / 256, 256, 0, stream>>>(x, x_bf);
    prep_w_kernel<<<(2 * 4 * 9 * 64 + 255) / 256, 256, 0, stream>>>(
        W_in, W_out, as_in, ad_in, as_out, ad_out, Wf);

    dim3 gemm_grid((N_NODES + 127) / 128, 2);
    gemm_kernel<<<gemm_grid, 256, 0, stream>>>(
        x_bf, Wf, h_in, h_out, asrc_in, adst_in, asrc_out, adst_out);

    zero_bcnt_kernel<<<(2 * N_BKT + 255) / 256, 256, 0, stream>>>(bcnt);
    bucket_hist_kernel<<<256, 256, 0, stream>>>(ei, bcnt);
    bucket_scan_kernel<<<2, 1024, 0, stream>>>(
        bcnt, boffs0, boffs1, bcur0, bcur1, offs_in, offs_out);
    bin_kernel<<<(N_EDGES + 255) / 256, 256, 0, stream>>>(
        ei, bcur0, bcur1, binned0, binned1);
    place_kernel<<<dim3(N_BKT, 2), 256, 0, stream>>>(
        binned0, binned1, boffs0, boffs1, adj_in, adj_out, offs_in, offs_out);

    gather_kernel<<<(N_NODES * 64 + 255) / 256, 256, 0, stream>>>(
        offs_in, adj_in, offs_out, adj_out, h_in, h_out,
        asrc_in, adst_in, asrc_out, adst_out, b_in, b_out, out);
}

// Round 6
// 303.734 us; speedup vs baseline: 1.8199x; 1.8199x over previous
//
#include <hip/hip_runtime.h>

#define N_NODES 100000
#define N_EDGES 800000
#define NEG 0.2f
#define PB_SHIFT 8
#define PB_NODES 256
#define N_PBKT ((N_NODES + PB_NODES - 1) / PB_NODES)   // 391
#define TILE_E 4096
#define EPT 16   // edges per thread in partition (TILE_E / 256)

typedef __attribute__((ext_vector_type(8))) short bf16x8;
typedef __attribute__((ext_vector_type(4))) float f32x4;

__device__ inline unsigned short f2bf(float f) {   // RNE f32 -> bf16
    unsigned u = __float_as_uint(f);
    u += 0x7fffu + ((u >> 16) & 1u);
    return (unsigned short)(u >> 16);
}
__device__ inline float bf2f_lo(unsigned u) { return __uint_as_float(u << 16); }
__device__ inline float bf2f_hi(unsigned u) { return __uint_as_float(u & 0xffff0000u); }

// ---------------------------------------------------------------------------
// prep_x: x f32 -> bf16 (shared by both GEMM directions)
// ---------------------------------------------------------------------------
__global__ __launch_bounds__(256) void prep_x_kernel(
    const float* __restrict__ x, unsigned short* __restrict__ x_bf)
{
    const int i = (blockIdx.x * 256 + threadIdx.x) * 4;
    if (i >= N_NODES * 128) return;
    const float4 v = *(const float4*)&x[i];
    ushort4 o;
    o.x = f2bf(v.x); o.y = f2bf(v.y); o.z = f2bf(v.z); o.w = f2bf(v.w);
    *(ushort4*)&x_bf[i] = o;
}

// ---------------------------------------------------------------------------
// prep_w: pack W (and Aalpha = W·a, ct==8) into MFMA B-fragment order.
// Also zeroes the bucket-count array (saves a launch).
// ---------------------------------------------------------------------------
__global__ __launch_bounds__(256) void prep_w_kernel(
    const float* __restrict__ W_in, const float* __restrict__ W_out,
    const float* __restrict__ as_in, const float* __restrict__ ad_in,
    const float* __restrict__ as_out, const float* __restrict__ ad_out,
    unsigned short* __restrict__ Wf, int* __restrict__ bcnt)
{
    const int t = blockIdx.x * 256 + threadIdx.x;
    if (t < 2 * N_PBKT) bcnt[t] = 0;
    if (t >= 2 * 4 * 9 * 64) return;
    const int lane = t & 63;
    const int rest = t >> 6;
    const int ct  = rest % 9;
    const int kb  = (rest / 9) & 3;
    const int dir = rest / 36;
    const float* W  = dir ? W_out  : W_in;
    const float* as = dir ? as_out : as_in;
    const float* ad = dir ? ad_out : ad_in;
    const int m16 = lane & 15, quad = lane >> 4;

    bf16x8 o;
#pragma unroll
    for (int j = 0; j < 8; ++j) {
        const int k = kb * 32 + quad * 8 + j;
        float v;
        if (ct < 8) {
            v = W[k * 128 + ct * 16 + m16];
        } else {
            const float* av = (m16 < 8) ? as : ad;
            const int hh = m16 & 7;
            v = 0.f;
            for (int c = 0; c < 16; ++c)
                v += W[k * 128 + hh * 16 + c] * av[hh * 16 + c];
        }
        o[j] = (short)f2bf(v);
    }
    *(bf16x8*)&Wf[(long long)t * 8] = o;
}

// ---------------------------------------------------------------------------
// gemm: h = bf16(x) @ bf16(W) via MFMA; alpha logits from the 9th column tile.
// ---------------------------------------------------------------------------
__global__ __launch_bounds__(256) void gemm_kernel(
    const unsigned short* __restrict__ x_bf,
    const unsigned short* __restrict__ Wf,
    unsigned short* __restrict__ h_in, unsigned short* __restrict__ h_out,
    float* __restrict__ asrc_in, float* __restrict__ adst_in,
    float* __restrict__ asrc_out, float* __restrict__ adst_out)
{
    const int dir = blockIdx.y;
    unsigned short* h = dir ? h_out : h_in;
    float* asrc = dir ? asrc_out : asrc_in;
    float* adst = dir ? adst_out : adst_in;

    const int tid  = threadIdx.x;
    const int lane = tid & 63;
    const int wave = tid >> 6;
    const int m16  = lane & 15;
    const int quad = lane >> 4;
    const int rbase = blockIdx.x * 128 + wave * 32;

    f32x4 acc[2][8];
    f32x4 acc_a[2];
#pragma unroll
    for (int rt = 0; rt < 2; ++rt) {
        acc_a[rt] = f32x4{0.f, 0.f, 0.f, 0.f};
#pragma unroll
        for (int ct = 0; ct < 8; ++ct)
            acc[rt][ct] = f32x4{0.f, 0.f, 0.f, 0.f};
    }

    const unsigned short* wf = Wf + (long long)dir * 4 * 9 * 64 * 8;

#pragma unroll
    for (int kb = 0; kb < 4; ++kb) {
        const int k0 = kb * 32 + quad * 8;
        bf16x8 a[2];
#pragma unroll
        for (int rt = 0; rt < 2; ++rt) {
            int r = rbase + rt * 16 + m16;
            r = r < N_NODES ? r : N_NODES - 1;   // clamp: stores are guarded
            a[rt] = *(const bf16x8*)&x_bf[(long long)r * 128 + k0];
        }
#pragma unroll
        for (int ct = 0; ct < 9; ++ct) {
            const bf16x8 b = *(const bf16x8*)&wf[(long long)((kb * 9 + ct) * 64 + lane) * 8];
            if (ct < 8) {
                acc[0][ct] = __builtin_amdgcn_mfma_f32_16x16x32_bf16(a[0], b, acc[0][ct], 0, 0, 0);
                acc[1][ct] = __builtin_amdgcn_mfma_f32_16x16x32_bf16(a[1], b, acc[1][ct], 0, 0, 0);
            } else {
                acc_a[0] = __builtin_amdgcn_mfma_f32_16x16x32_bf16(a[0], b, acc_a[0], 0, 0, 0);
                acc_a[1] = __builtin_amdgcn_mfma_f32_16x16x32_bf16(a[1], b, acc_a[1], 0, 0, 0);
            }
        }
    }

#pragma unroll
    for (int rt = 0; rt < 2; ++rt) {
#pragma unroll
        for (int r = 0; r < 4; ++r) {
            const int row = rbase + rt * 16 + quad * 4 + r;
            if (row < N_NODES) {
                unsigned short* hp = &h[(long long)row * 128 + m16];
#pragma unroll
                for (int ct = 0; ct < 8; ++ct)
                    hp[ct * 16] = f2bf(acc[rt][ct][r]);
                const float av = acc_a[rt][r];
                if (m16 < 8) asrc[row * 8 + m16] = av;
                else         adst[row * 8 + (m16 - 8)] = av;
            }
        }
    }
}

// ---------------------------------------------------------------------------
// CSR build v3: radix-style partition with block-staged reservation.
// ---------------------------------------------------------------------------
// pass A: coarse bucket histogram (LDS-staged, low-contention flush)
__global__ __launch_bounds__(256) void bucket_hist_kernel(
    const int* __restrict__ ei, int* __restrict__ bcnt)
{
    __shared__ int bh[2 * N_PBKT];
    const int tid = threadIdx.x;
    for (int i = tid; i < 2 * N_PBKT; i += 256) bh[i] = 0;
    __syncthreads();
    for (int e = blockIdx.x * 256 + tid; e < N_EDGES; e += gridDim.x * 256) {
        const int s = ei[e];
        const int t = ei[N_EDGES + e];
        atomicAdd(&bh[t >> PB_SHIFT], 1);               // dir0: group by dst
        atomicAdd(&bh[N_PBKT + (s >> PB_SHIFT)], 1);    // dir1: group by src
    }
    __syncthreads();
    for (int i = tid; i < 2 * N_PBKT; i += 256) {
        const int v = bh[i];
        if (v) atomicAdd(&bcnt[i], v);
    }
}

// pass B: scan bucket counts -> boffs (persistent) + gcur (consumed)
__global__ __launch_bounds__(512) void bucket_scan_kernel(
    const int* __restrict__ bcnt,
    int* __restrict__ boffs0, int* __restrict__ boffs1,
    int* __restrict__ gcur,
    int* __restrict__ offs_in, int* __restrict__ offs_out)
{
    const int dir = blockIdx.x;
    const int* c = bcnt + dir * N_PBKT;
    int* bo = dir ? boffs1 : boffs0;
    int* gc = gcur + dir * N_PBKT;

    __shared__ int sm[512];
    const int tid = threadIdx.x;
    const int v = (tid < N_PBKT) ? c[tid] : 0;
    sm[tid] = v;
    __syncthreads();
#pragma unroll
    for (int off = 1; off < 512; off <<= 1) {
        int t = (tid >= off) ? sm[tid - off] : 0;
        __syncthreads();
        sm[tid] += t;
        __syncthreads();
    }
    if (tid < N_PBKT) {
        const int excl = sm[tid] - v;
        bo[tid] = excl;
        gc[tid] = excl;
    }
    if (tid == N_PBKT - 1) bo[N_PBKT] = sm[tid];   // == N_EDGES
    if (tid == 0) (dir ? offs_out : offs_in)[N_NODES] = N_EDGES;
}

// pass C: partition. Tile of 4096 edges in registers; LDS hist; one global
// atomic per (block,bucket); clustered writes via LDS cursors. Pair packed
// as (val<<8)|key_low (val < 2^17, fits with room to spare).
__global__ __launch_bounds__(256) void partition_kernel(
    const int* __restrict__ ei, int* __restrict__ gcur,
    int* __restrict__ binned0, int* __restrict__ binned1)
{
    const int dir = blockIdx.y;
    int* binned = dir ? binned1 : binned0;
    int* gc = gcur + dir * N_PBKT;

    __shared__ int hist[N_PBKT];
    __shared__ int curs[N_PBKT];
    const int tid = threadIdx.x;
    for (int i = tid; i < N_PBKT; i += 256) hist[i] = 0;
    __syncthreads();

    const int e0 = blockIdx.x * TILE_E;
    int key[EPT], val[EPT];
#pragma unroll
    for (int i = 0; i < EPT; ++i) {
        const int e = e0 + i * 256 + tid;
        if (e < N_EDGES) {
            const int s = ei[e];
            const int t = ei[N_EDGES + e];
            key[i] = dir ? s : t;
            val[i] = dir ? t : s;
            atomicAdd(&hist[key[i] >> PB_SHIFT], 1);
        } else {
            key[i] = -1; val[i] = 0;
        }
    }
    __syncthreads();
    for (int b = tid; b < N_PBKT; b += 256) {
        const int c = hist[b];
        curs[b] = c ? atomicAdd(&gc[b], c) : 0;
    }
    __syncthreads();
#pragma unroll
    for (int i = 0; i < EPT; ++i) {
        if (key[i] >= 0) {
            const int pos = atomicAdd(&curs[key[i] >> PB_SHIFT], 1);
            binned[pos] = (val[i] << 8) | (key[i] & (PB_NODES - 1));
        }
    }
}

// pass D: one block per bucket; fine count+scan+cursors in LDS; adj writes
// land in a contiguous ~8KB region (lines fully dirtied).
__global__ __launch_bounds__(256) void place_kernel(
    const int* __restrict__ binned0, const int* __restrict__ binned1,
    const int* __restrict__ boffs0, const int* __restrict__ boffs1,
    int* __restrict__ adj_in, int* __restrict__ adj_out,
    int* __restrict__ offs_in, int* __restrict__ offs_out)
{
    const int b   = blockIdx.x;
    const int dir = blockIdx.y;
    const int* bp = dir ? binned1 : binned0;
    const int* bo = dir ? boffs1  : boffs0;
    int* adj  = dir ? adj_out  : adj_in;
    int* offs = dir ? offs_out : offs_in;

    const int base = b << PB_SHIFT;
    const int beg = bo[b], end = bo[b + 1];
    const int tid = threadIdx.x;

    __shared__ int cnt[PB_NODES];
    __shared__ int sc[PB_NODES];
    __shared__ int cur[PB_NODES];

    cnt[tid] = 0;
    __syncthreads();
    for (int p = beg + tid; p < end; p += 256)
        atomicAdd(&cnt[bp[p] & (PB_NODES - 1)], 1);
    __syncthreads();
    const int v = cnt[tid];
    sc[tid] = v;
    __syncthreads();
#pragma unroll
    for (int off = 1; off < PB_NODES; off <<= 1) {
        int t = (tid >= off) ? sc[tid - off] : 0;
        __syncthreads();
        sc[tid] += t;
        __syncthreads();
    }
    const int excl = beg + sc[tid] - v;
    cur[tid] = excl;
    const int node = base + tid;
    if (node < N_NODES) offs[node] = excl;
    __syncthreads();
    for (int p = beg + tid; p < end; p += 256) {
        const int pk = bp[p];
        adj[atomicAdd(&cur[pk & (PB_NODES - 1)], 1)] = pk >> 8;
    }
}

// ---------------------------------------------------------------------------
// Gather: one wave per node, both directions + bias, unrolled x4 for MLP.
// ---------------------------------------------------------------------------
__global__ __launch_bounds__(256) void gather_kernel(
    const int* __restrict__ offs_in, const int* __restrict__ adj_in,
    const int* __restrict__ offs_out, const int* __restrict__ adj_out,
    const unsigned short* __restrict__ h_in, const unsigned short* __restrict__ h_out,
    const float* __restrict__ asrc_in, const float* __restrict__ adst_in,
    const float* __restrict__ asrc_out, const float* __restrict__ adst_out,
    const float* __restrict__ b_in, const float* __restrict__ b_out,
    float* __restrict__ out)
{
    const int n = (blockIdx.x * 256 + threadIdx.x) >> 6;
    if (n >= N_NODES) return;
    const int lane = threadIdx.x & 63;
    const int c0 = lane * 2;
    const int hh = lane >> 3;

    float acc0 = b_in[c0] + b_out[c0];
    float acc1 = b_in[c0 + 1] + b_out[c0 + 1];

#define DIR_BLOCK(OFFS, ADJ, HX, ASRC, ADST)                                   \
    {                                                                          \
        const int beg = OFFS[n], end = OFFS[n + 1];                            \
        if (end > beg) {                                                       \
            const float ad = ADST[n * 8 + hh];                                 \
            float num0 = 0.f, num1 = 0.f, den = 0.f;                           \
            int p = beg;                                                       \
            for (; p + 4 <= end; p += 4) {                                     \
                const int nb0 = ADJ[p], nb1 = ADJ[p + 1];                      \
                const int nb2 = ADJ[p + 2], nb3 = ADJ[p + 3];                  \
                const float s0 = ASRC[nb0 * 8 + hh], s1 = ASRC[nb1 * 8 + hh];  \
                const float s2 = ASRC[nb2 * 8 + hh], s3 = ASRC[nb3 * 8 + hh];  \
                const unsigned v0 = *(const unsigned*)&HX[(long long)nb0 * 128 + c0]; \
                const unsigned v1 = *(const unsigned*)&HX[(long long)nb1 * 128 + c0]; \
                const unsigned v2 = *(const unsigned*)&HX[(long long)nb2 * 128 + c0]; \
                const unsigned v3 = *(const unsigned*)&HX[(long long)nb3 * 128 + c0]; \
                float l0 = s0 + ad; l0 = l0 > 0.f ? l0 : NEG * l0;             \
                float l1 = s1 + ad; l1 = l1 > 0.f ? l1 : NEG * l1;             \
                float l2 = s2 + ad; l2 = l2 > 0.f ? l2 : NEG * l2;             \
                float l3 = s3 + ad; l3 = l3 > 0.f ? l3 : NEG * l3;             \
                const float w0 = __expf(l0), w1 = __expf(l1);                  \
                const float w2 = __expf(l2), w3 = __expf(l3);                  \
                den += (w0 + w1) + (w2 + w3);                                  \
                num0 += w0 * bf2f_lo(v0) + w1 * bf2f_lo(v1)                    \
                      + w2 * bf2f_lo(v2) + w3 * bf2f_lo(v3);                   \
                num1 += w0 * bf2f_hi(v0) + w1 * bf2f_hi(v1)                    \
                      + w2 * bf2f_hi(v2) + w3 * bf2f_hi(v3);                   \
            }                                                                  \
            for (; p < end; ++p) {                                             \
                const int nb = ADJ[p];                                         \
                float l = ASRC[nb * 8 + hh] + ad;                              \
                l = l > 0.f ? l : NEG * l;                                     \
                const float w = __expf(l);                                     \
                den += w;                                                      \
                const unsigned hv = *(const unsigned*)&HX[(long long)nb * 128 + c0]; \
                num0 += w * bf2f_lo(hv);                                       \
                num1 += w * bf2f_hi(hv);                                       \
            }                                                                  \
            acc0 += num0 / den;                                                \
            acc1 += num1 / den;                                                \
        }                                                                      \
    }

    DIR_BLOCK(offs_in, adj_in, h_in, asrc_in, adst_in)
    DIR_BLOCK(offs_out, adj_out, h_out, asrc_out, adst_out)
#undef DIR_BLOCK

    *(float2*)&out[(long long)n * 128 + c0] = float2{acc0, acc1};
}

extern "C" void kernel_launch(void* const* d_in, const int* in_sizes, int n_in,
                              void* d_out, int out_size, void* d_ws, size_t ws_size,
                              hipStream_t stream) {
    const float* x      = (const float*)d_in[0];
    const int*   ei     = (const int*)  d_in[1];
    const float* W_in   = (const float*)d_in[2];
    const float* as_in  = (const float*)d_in[3];
    const float* ad_in  = (const float*)d_in[4];
    const float* b_in   = (const float*)d_in[5];
    const float* W_out  = (const float*)d_in[6];
    const float* as_out = (const float*)d_in[7];
    const float* ad_out = (const float*)d_in[8];
    const float* b_out  = (const float*)d_in[9];
    float* out = (float*)d_out;

    char* ws = (char*)d_ws;
    const long long NH = (long long)N_NODES * 128;
    unsigned short* x_bf  = (unsigned short*)ws;    ws += NH * 2;
    unsigned short* h_in  = (unsigned short*)ws;    ws += NH * 2;
    unsigned short* h_out = (unsigned short*)ws;    ws += NH * 2;
    unsigned short* Wf    = (unsigned short*)ws;    ws += 2LL * 4 * 9 * 64 * 8 * 2;
    float* asrc_in   = (float*)ws;                  ws += N_NODES * 8 * 4;
    float* adst_in   = (float*)ws;                  ws += N_NODES * 8 * 4;
    float* asrc_out  = (float*)ws;                  ws += N_NODES * 8 * 4;
    float* adst_out  = (float*)ws;                  ws += N_NODES * 8 * 4;
    int* binned0     = (int*)ws;                    ws += (long long)N_EDGES * 4;
    int* binned1     = (int*)ws;                    ws += (long long)N_EDGES * 4;
    int* adj_in      = (int*)ws;                    ws += N_EDGES * 4;
    int* adj_out     = (int*)ws;                    ws += N_EDGES * 4;
    int* offs_in     = (int*)ws;                    ws += (N_NODES + 1) * 4;
    int* offs_out    = (int*)ws;                    ws += (N_NODES + 1) * 4;
    int* bcnt        = (int*)ws;                    ws += 2 * N_PBKT * 4;
    int* boffs0      = (int*)ws;                    ws += (N_PBKT + 1) * 4;
    int* boffs1      = (int*)ws;                    ws += (N_PBKT + 1) * 4;
    int* gcur        = (int*)ws;                    ws += 2 * N_PBKT * 4;

    prep_x_kernel<<<(N_NODES * 128 / 4 + 255) / 256, 256, 0, stream>>>(x, x_bf);
    prep_w_kernel<<<(2 * 4 * 9 * 64 + 255) / 256, 256, 0, stream>>>(
        W_in, W_out, as_in, ad_in, as_out, ad_out, Wf, bcnt);

    dim3 gemm_grid((N_NODES + 127) / 128, 2);
    gemm_kernel<<<gemm_grid, 256, 0, stream>>>(
        x_bf, Wf, h_in, h_out, asrc_in, adst_in, asrc_out, adst_out);

    bucket_hist_kernel<<<192, 256, 0, stream>>>(ei, bcnt);
    bucket_scan_kernel<<<2, 512, 0, stream>>>(
        bcnt, boffs0, boffs1, gcur, offs_in, offs_out);
    partition_kernel<<<dim3((N_EDGES + TILE_E - 1) / TILE_E, 2), 256, 0, stream>>>(
        ei, gcur, binned0, binned1);
    place_kernel<<<dim3(N_PBKT, 2), 256, 0, stream>>>(
        binned0, binned1, boffs0, boffs1, adj_in, adj_out, offs_in, offs_out);

    gather_kernel<<<(N_NODES * 64 + 255) / 256, 256, 0, stream>>>(
        offs_in, adj_in, offs_out, adj_out, h_in, h_out,
        asrc_in, adst_in, asrc_out, adst_out, b_in, b_out, out);
}

// Round 7
// 303.385 us; speedup vs baseline: 1.8220x; 1.0012x over previous
//
#include <hip/hip_runtime.h>

#define N_NODES 100000
#define N_EDGES 800000
#define NEG 0.2f
#define PB_SHIFT 8
#define PB_NODES 256
#define N_PBKT ((N_NODES + PB_NODES - 1) / PB_NODES)   // 391
#define TILE_E 4096
#define EPT 16          // edges per thread in partition (TILE_E / 256)
#define PREP_BLOCKS ((N_NODES * 128 / 4 + 255) / 256)  // 12500
#define HIST_BLOCKS 192

typedef __attribute__((ext_vector_type(8))) short bf16x8;
typedef __attribute__((ext_vector_type(4))) float f32x4;

__device__ inline unsigned short f2bf(float f) {   // RNE f32 -> bf16
    unsigned u = __float_as_uint(f);
    u += 0x7fffu + ((u >> 16) & 1u);
    return (unsigned short)(u >> 16);
}
__device__ inline float bf2f_lo(unsigned u) { return __uint_as_float(u << 16); }
__device__ inline float bf2f_hi(unsigned u) { return __uint_as_float(u & 0xffff0000u); }

// ---------------------------------------------------------------------------
// prep_w: pack W (and Aalpha = W·a, ct==8) into MFMA B-fragment order.
// Also zeroes the bucket-count array (consumed by the fused hist below).
// ---------------------------------------------------------------------------
__global__ __launch_bounds__(256) void prep_w_kernel(
    const float* __restrict__ W_in, const float* __restrict__ W_out,
    const float* __restrict__ as_in, const float* __restrict__ ad_in,
    const float* __restrict__ as_out, const float* __restrict__ ad_out,
    unsigned short* __restrict__ Wf, int* __restrict__ bcnt)
{
    const int t = blockIdx.x * 256 + threadIdx.x;
    if (t < 2 * N_PBKT) bcnt[t] = 0;
    if (t >= 2 * 4 * 9 * 64) return;
    const int lane = t & 63;
    const int rest = t >> 6;
    const int ct  = rest % 9;
    const int kb  = (rest / 9) & 3;
    const int dir = rest / 36;
    const float* W  = dir ? W_out  : W_in;
    const float* as = dir ? as_out : as_in;
    const float* ad = dir ? ad_out : ad_in;
    const int m16 = lane & 15, quad = lane >> 4;

    bf16x8 o;
#pragma unroll
    for (int j = 0; j < 8; ++j) {
        const int k = kb * 32 + quad * 8 + j;
        float v;
        if (ct < 8) {
            v = W[k * 128 + ct * 16 + m16];
        } else {
            const float* av = (m16 < 8) ? as : ad;
            const int hh = m16 & 7;
            v = 0.f;
            for (int c = 0; c < 16; ++c)
                v += W[k * 128 + hh * 16 + c] * av[hh * 16 + c];
        }
        o[j] = (short)f2bf(v);
    }
    *(bf16x8*)&Wf[(long long)t * 8] = o;
}

// ---------------------------------------------------------------------------
// fused prep_x + coarse bucket histogram.
// blocks [0, PREP_BLOCKS): x f32 -> bf16 conversion.
// blocks [PREP_BLOCKS, PREP_BLOCKS+HIST_BLOCKS): LDS-staged bucket histogram.
// ---------------------------------------------------------------------------
__global__ __launch_bounds__(256) void prep_hist_kernel(
    const float* __restrict__ x, unsigned short* __restrict__ x_bf,
    const int* __restrict__ ei, int* __restrict__ bcnt)
{
    const int tid = threadIdx.x;
    if (blockIdx.x < PREP_BLOCKS) {
        const int i = (blockIdx.x * 256 + tid) * 4;
        if (i >= N_NODES * 128) return;
        const float4 v = *(const float4*)&x[i];
        ushort4 o;
        o.x = f2bf(v.x); o.y = f2bf(v.y); o.z = f2bf(v.z); o.w = f2bf(v.w);
        *(ushort4*)&x_bf[i] = o;
        return;
    }
    // histogram part
    __shared__ int bh[2 * N_PBKT];
    for (int i = tid; i < 2 * N_PBKT; i += 256) bh[i] = 0;
    __syncthreads();
    const int hb = blockIdx.x - PREP_BLOCKS;
    for (int e = hb * 256 + tid; e < N_EDGES; e += HIST_BLOCKS * 256) {
        const int s = ei[e];
        const int t = ei[N_EDGES + e];
        atomicAdd(&bh[t >> PB_SHIFT], 1);               // dir0: group by dst
        atomicAdd(&bh[N_PBKT + (s >> PB_SHIFT)], 1);    // dir1: group by src
    }
    __syncthreads();
    for (int i = tid; i < 2 * N_PBKT; i += 256) {
        const int v = bh[i];
        if (v) atomicAdd(&bcnt[i], v);
    }
}

// ---------------------------------------------------------------------------
// gemm: h = bf16(x) @ bf16(W) via MFMA; alpha logits from the 9th column tile.
// ---------------------------------------------------------------------------
__global__ __launch_bounds__(256) void gemm_kernel(
    const unsigned short* __restrict__ x_bf,
    const unsigned short* __restrict__ Wf,
    unsigned short* __restrict__ h_in, unsigned short* __restrict__ h_out,
    float* __restrict__ asrc_in, float* __restrict__ adst_in,
    float* __restrict__ asrc_out, float* __restrict__ adst_out)
{
    const int dir = blockIdx.y;
    unsigned short* h = dir ? h_out : h_in;
    float* asrc = dir ? asrc_out : asrc_in;
    float* adst = dir ? adst_out : adst_in;

    const int tid  = threadIdx.x;
    const int lane = tid & 63;
    const int wave = tid >> 6;
    const int m16  = lane & 15;
    const int quad = lane >> 4;
    const int rbase = blockIdx.x * 128 + wave * 32;

    f32x4 acc[2][8];
    f32x4 acc_a[2];
#pragma unroll
    for (int rt = 0; rt < 2; ++rt) {
        acc_a[rt] = f32x4{0.f, 0.f, 0.f, 0.f};
#pragma unroll
        for (int ct = 0; ct < 8; ++ct)
            acc[rt][ct] = f32x4{0.f, 0.f, 0.f, 0.f};
    }

    const unsigned short* wf = Wf + (long long)dir * 4 * 9 * 64 * 8;

#pragma unroll
    for (int kb = 0; kb < 4; ++kb) {
        const int k0 = kb * 32 + quad * 8;
        bf16x8 a[2];
#pragma unroll
        for (int rt = 0; rt < 2; ++rt) {
            int r = rbase + rt * 16 + m16;
            r = r < N_NODES ? r : N_NODES - 1;   // clamp: stores are guarded
            a[rt] = *(const bf16x8*)&x_bf[(long long)r * 128 + k0];
        }
#pragma unroll
        for (int ct = 0; ct < 9; ++ct) {
            const bf16x8 b = *(const bf16x8*)&wf[(long long)((kb * 9 + ct) * 64 + lane) * 8];
            if (ct < 8) {
                acc[0][ct] = __builtin_amdgcn_mfma_f32_16x16x32_bf16(a[0], b, acc[0][ct], 0, 0, 0);
                acc[1][ct] = __builtin_amdgcn_mfma_f32_16x16x32_bf16(a[1], b, acc[1][ct], 0, 0, 0);
            } else {
                acc_a[0] = __builtin_amdgcn_mfma_f32_16x16x32_bf16(a[0], b, acc_a[0], 0, 0, 0);
                acc_a[1] = __builtin_amdgcn_mfma_f32_16x16x32_bf16(a[1], b, acc_a[1], 0, 0, 0);
            }
        }
    }

#pragma unroll
    for (int rt = 0; rt < 2; ++rt) {
#pragma unroll
        for (int r = 0; r < 4; ++r) {
            const int row = rbase + rt * 16 + quad * 4 + r;
            if (row < N_NODES) {
                unsigned short* hp = &h[(long long)row * 128 + m16];
#pragma unroll
                for (int ct = 0; ct < 8; ++ct)
                    hp[ct * 16] = f2bf(acc[rt][ct][r]);
                const float av = acc_a[rt][r];
                if (m16 < 8) asrc[row * 8 + m16] = av;
                else         adst[row * 8 + (m16 - 8)] = av;
            }
        }
    }
}

// ---------------------------------------------------------------------------
// CSR build: scan bucket counts -> boffs (persistent) + gcur (consumed)
// ---------------------------------------------------------------------------
__global__ __launch_bounds__(512) void bucket_scan_kernel(
    const int* __restrict__ bcnt,
    int* __restrict__ boffs0, int* __restrict__ boffs1,
    int* __restrict__ gcur,
    int* __restrict__ offs_in, int* __restrict__ offs_out)
{
    const int dir = blockIdx.x;
    const int* c = bcnt + dir * N_PBKT;
    int* bo = dir ? boffs1 : boffs0;
    int* gc = gcur + dir * N_PBKT;

    __shared__ int sm[512];
    const int tid = threadIdx.x;
    const int v = (tid < N_PBKT) ? c[tid] : 0;
    sm[tid] = v;
    __syncthreads();
#pragma unroll
    for (int off = 1; off < 512; off <<= 1) {
        int t = (tid >= off) ? sm[tid - off] : 0;
        __syncthreads();
        sm[tid] += t;
        __syncthreads();
    }
    if (tid < N_PBKT) {
        const int excl = sm[tid] - v;
        bo[tid] = excl;
        gc[tid] = excl;
    }
    if (tid == N_PBKT - 1) bo[N_PBKT] = sm[tid];   // == N_EDGES
    if (tid == 0) (dir ? offs_out : offs_in)[N_NODES] = N_EDGES;
}

// partition: tile of 4096 edges in registers; LDS hist; one global atomic per
// (block,bucket); clustered writes via LDS cursors. Pair packed (val<<8)|keylow.
__global__ __launch_bounds__(256) void partition_kernel(
    const int* __restrict__ ei, int* __restrict__ gcur,
    int* __restrict__ binned0, int* __restrict__ binned1)
{
    const int dir = blockIdx.y;
    int* binned = dir ? binned1 : binned0;
    int* gc = gcur + dir * N_PBKT;

    __shared__ int hist[N_PBKT];
    __shared__ int curs[N_PBKT];
    const int tid = threadIdx.x;
    for (int i = tid; i < N_PBKT; i += 256) hist[i] = 0;
    __syncthreads();

    const int e0 = blockIdx.x * TILE_E;
    int key[EPT], val[EPT];
#pragma unroll
    for (int i = 0; i < EPT; ++i) {
        const int e = e0 + i * 256 + tid;
        if (e < N_EDGES) {
            const int s = ei[e];
            const int t = ei[N_EDGES + e];
            key[i] = dir ? s : t;
            val[i] = dir ? t : s;
            atomicAdd(&hist[key[i] >> PB_SHIFT], 1);
        } else {
            key[i] = -1; val[i] = 0;
        }
    }
    __syncthreads();
    for (int b = tid; b < N_PBKT; b += 256) {
        const int c = hist[b];
        curs[b] = c ? atomicAdd(&gc[b], c) : 0;
    }
    __syncthreads();
#pragma unroll
    for (int i = 0; i < EPT; ++i) {
        if (key[i] >= 0) {
            const int pos = atomicAdd(&curs[key[i] >> PB_SHIFT], 1);
            binned[pos] = (val[i] << 8) | (key[i] & (PB_NODES - 1));
        }
    }
}

// place: one block per bucket; fine count+scan+cursors in LDS; adj writes
// land in a contiguous ~8KB region.
__global__ __launch_bounds__(256) void place_kernel(
    const int* __restrict__ binned0, const int* __restrict__ binned1,
    const int* __restrict__ boffs0, const int* __restrict__ boffs1,
    int* __restrict__ adj_in, int* __restrict__ adj_out,
    int* __restrict__ offs_in, int* __restrict__ offs_out)
{
    const int b   = blockIdx.x;
    const int dir = blockIdx.y;
    const int* bp = dir ? binned1 : binned0;
    const int* bo = dir ? boffs1  : boffs0;
    int* adj  = dir ? adj_out  : adj_in;
    int* offs = dir ? offs_out : offs_in;

    const int base = b << PB_SHIFT;
    const int beg = bo[b], end = bo[b + 1];
    const int tid = threadIdx.x;

    __shared__ int cnt[PB_NODES];
    __shared__ int sc[PB_NODES];
    __shared__ int cur[PB_NODES];

    cnt[tid] = 0;
    __syncthreads();
    for (int p = beg + tid; p < end; p += 256)
        atomicAdd(&cnt[bp[p] & (PB_NODES - 1)], 1);
    __syncthreads();
    const int v = cnt[tid];
    sc[tid] = v;
    __syncthreads();
#pragma unroll
    for (int off = 1; off < PB_NODES; off <<= 1) {
        int t = (tid >= off) ? sc[tid - off] : 0;
        __syncthreads();
        sc[tid] += t;
        __syncthreads();
    }
    const int excl = beg + sc[tid] - v;
    cur[tid] = excl;
    const int node = base + tid;
    if (node < N_NODES) offs[node] = excl;
    __syncthreads();
    for (int p = beg + tid; p < end; p += 256) {
        const int pk = bp[p];
        adj[atomicAdd(&cur[pk & (PB_NODES - 1)], 1)] = pk >> 8;
    }
}

// ---------------------------------------------------------------------------
// Gather v2: one wave per node. Neighbors processed in groups of 8: the 64
// lanes compute exp for all 8x8 (neighbor, head) combos at once (1 exp per
// 8 neighbors instead of 8), then w/nbr broadcast within each 8-lane head
// group via __shfl (LDS pipe). den kept as per-lane partials, butterfly-
// reduced once at the end. 8 concurrent h-row loads per group.
// ---------------------------------------------------------------------------
__global__ __launch_bounds__(256) void gather_kernel(
    const int* __restrict__ offs_in, const int* __restrict__ adj_in,
    const int* __restrict__ offs_out, const int* __restrict__ adj_out,
    const unsigned short* __restrict__ h_in, const unsigned short* __restrict__ h_out,
    const float* __restrict__ asrc_in, const float* __restrict__ adst_in,
    const float* __restrict__ asrc_out, const float* __restrict__ adst_out,
    const float* __restrict__ b_in, const float* __restrict__ b_out,
    float* __restrict__ out)
{
    const int n = (blockIdx.x * 256 + threadIdx.x) >> 6;
    if (n >= N_NODES) return;
    const int lane = threadIdx.x & 63;
    const int c0 = lane * 2;
    const int hh = lane >> 3;        // head this lane accumulates for
    const int g8 = lane & 7;         // neighbor slot this lane exps
    const int grpbase = lane & 56;   // hh*8: base lane of this head group

    float acc0 = b_in[c0] + b_out[c0];
    float acc1 = b_in[c0 + 1] + b_out[c0 + 1];

#define DIR_BLOCK(OFFS, ADJ, HX, ASRC, ADST)                                   \
    {                                                                          \
        const int beg = OFFS[n], end = OFFS[n + 1];                            \
        if (end > beg) {                                                       \
            const float ad = ADST[n * 8 + hh];                                 \
            float num0 = 0.f, num1 = 0.f, den = 0.f;                           \
            int p = beg;                                                       \
            for (; p + 8 <= end; p += 8) {                                     \
                const int nb_mine = ADJ[p + g8];                               \
                float l = ASRC[nb_mine * 8 + hh] + ad;                         \
                l = l > 0.f ? l : NEG * l;                                     \
                const float w = __expf(l);                                     \
                den += w;                                                      \
                _Pragma("unroll")                                              \
                for (int g = 0; g < 8; ++g) {                                  \
                    const int   nb_g = __shfl(nb_mine, grpbase + g, 64);       \
                    const float w_g  = __shfl(w, grpbase + g, 64);             \
                    const unsigned hv = *(const unsigned*)&HX[(long long)nb_g * 128 + c0]; \
                    num0 += w_g * bf2f_lo(hv);                                 \
                    num1 += w_g * bf2f_hi(hv);                                 \
                }                                                              \
            }                                                                  \
            if (p < end) {                                                     \
                const int q = p + g8;                                          \
                const int nb_mine = (q < end) ? ADJ[q] : 0;                    \
                float w = 0.f;                                                 \
                if (q < end) {                                                 \
                    float l = ASRC[nb_mine * 8 + hh] + ad;                     \
                    l = l > 0.f ? l : NEG * l;                                 \
                    w = __expf(l);                                             \
                }                                                              \
                den += w;                                                      \
                const int cnt_t = end - p;                                     \
                for (int g = 0; g < cnt_t; ++g) {                              \
                    const int   nb_g = __shfl(nb_mine, grpbase + g, 64);       \
                    const float w_g  = __shfl(w, grpbase + g, 64);             \
                    const unsigned hv = *(const unsigned*)&HX[(long long)nb_g * 128 + c0]; \
                    num0 += w_g * bf2f_lo(hv);                                 \
                    num1 += w_g * bf2f_hi(hv);                                 \
                }                                                              \
            }                                                                  \
            den += __shfl_xor(den, 1, 64);                                     \
            den += __shfl_xor(den, 2, 64);                                     \
            den += __shfl_xor(den, 4, 64);                                     \
            acc0 += num0 / den;                                                \
            acc1 += num1 / den;                                                \
        }                                                                      \
    }

    DIR_BLOCK(offs_in, adj_in, h_in, asrc_in, adst_in)
    DIR_BLOCK(offs_out, adj_out, h_out, asrc_out, adst_out)
#undef DIR_BLOCK

    *(float2*)&out[(long long)n * 128 + c0] = float2{acc0, acc1};
}

extern "C" void kernel_launch(void* const* d_in, const int* in_sizes, int n_in,
                              void* d_out, int out_size, void* d_ws, size_t ws_size,
                              hipStream_t stream) {
    const float* x      = (const float*)d_in[0];
    const int*   ei     = (const int*)  d_in[1];
    const float* W_in   = (const float*)d_in[2];
    const float* as_in  = (const float*)d_in[3];
    const float* ad_in  = (const float*)d_in[4];
    const float* b_in   = (const float*)d_in[5];
    const float* W_out  = (const float*)d_in[6];
    const float* as_out = (const float*)d_in[7];
    const float* ad_out = (const float*)d_in[8];
    const float* b_out  = (const float*)d_in[9];
    float* out = (float*)d_out;

    char* ws = (char*)d_ws;
    const long long NH = (long long)N_NODES * 128;
    unsigned short* x_bf  = (unsigned short*)ws;    ws += NH * 2;
    unsigned short* h_in  = (unsigned short*)ws;    ws += NH * 2;
    unsigned short* h_out = (unsigned short*)ws;    ws += NH * 2;
    unsigned short* Wf    = (unsigned short*)ws;    ws += 2LL * 4 * 9 * 64 * 8 * 2;
    float* asrc_in   = (float*)ws;                  ws += N_NODES * 8 * 4;
    float* adst_in   = (float*)ws;                  ws += N_NODES * 8 * 4;
    float* asrc_out  = (float*)ws;                  ws += N_NODES * 8 * 4;
    float* adst_out  = (float*)ws;                  ws += N_NODES * 8 * 4;
    int* binned0     = (int*)ws;                    ws += (long long)N_EDGES * 4;
    int* binned1     = (int*)ws;                    ws += (long long)N_EDGES * 4;
    int* adj_in      = (int*)ws;                    ws += N_EDGES * 4;
    int* adj_out     = (int*)ws;                    ws += N_EDGES * 4;
    int* offs_in     = (int*)ws;                    ws += (N_NODES + 1) * 4;
    int* offs_out    = (int*)ws;                    ws += (N_NODES + 1) * 4;
    int* bcnt        = (int*)ws;                    ws += 2 * N_PBKT * 4;
    int* boffs0      = (int*)ws;                    ws += (N_PBKT + 1) * 4;
    int* boffs1      = (int*)ws;                    ws += (N_PBKT + 1) * 4;
    int* gcur        = (int*)ws;                    ws += 2 * N_PBKT * 4;

    prep_w_kernel<<<(2 * 4 * 9 * 64 + 255) / 256, 256, 0, stream>>>(
        W_in, W_out, as_in, ad_in, as_out, ad_out, Wf, bcnt);
    prep_hist_kernel<<<PREP_BLOCKS + HIST_BLOCKS, 256, 0, stream>>>(
        x, x_bf, ei, bcnt);

    dim3 gemm_grid((N_NODES + 127) / 128, 2);
    gemm_kernel<<<gemm_grid, 256, 0, stream>>>(
        x_bf, Wf, h_in, h_out, asrc_in, adst_in, asrc_out, adst_out);

    bucket_scan_kernel<<<2, 512, 0, stream>>>(
        bcnt, boffs0, boffs1, gcur, offs_in, offs_out);
    partition_kernel<<<dim3((N_EDGES + TILE_E - 1) / TILE_E, 2), 256, 0, stream>>>(
        ei, gcur, binned0, binned1);
    place_kernel<<<dim3(N_PBKT, 2), 256, 0, stream>>>(
        binned0, binned1, boffs0, boffs1, adj_in, adj_out, offs_in, offs_out);

    gather_kernel<<<(N_NODES * 64 + 255) / 256, 256, 0, stream>>>(
        offs_in, adj_in, offs_out, adj_out, h_in, h_out,
        asrc_in, adst_in, asrc_out, adst_out, b_in, b_out, out);
}